// Round 7
// baseline (293.081 us; speedup 1.0000x reference)
//
#include <hip/hip_runtime.h>
#include <math.h>

#define S_LEN 2048
#define D_KV  64
#define BQ    128   // q rows per block: 4 q-waves x 32 (x2 split-K groups)
#define BK    64
#define KHALF 1024
#define NT    (KHALF / BK)   // 16 k-tiles per split-K group

typedef __attribute__((ext_vector_type(8)))  short bh8;   // 8 bf16 (MFMA A/B frag)
typedef __attribute__((ext_vector_type(4)))  float fx4;
typedef __attribute__((ext_vector_type(16))) float fx16;  // 32x32 MFMA C/D frag
typedef __attribute__((ext_vector_type(4)))  unsigned int u32x4;
typedef __attribute__((ext_vector_type(2)))  unsigned int u32x2;

__device__ __forceinline__ unsigned cvt2(float a, float b) {
    unsigned r;
    asm("v_cvt_pk_bf16_f32 %0, %1, %2" : "=v"(r) : "v"(a), "v"(b));
    return r;
}
// v_permlane32_swap_b32 d, s: exchanges d lanes 32-63 with s lanes 0-31.
__device__ __forceinline__ void swap32(unsigned &d, unsigned &s) {
    asm("v_permlane32_swap_b32 %0, %1" : "+v"(d), "+v"(s));
}
__device__ __forceinline__ float exp2_fast(float x) {   // native 2^x
    float r;
    asm("v_exp_f32 %0, %1" : "=v"(r) : "v"(x));
    return r;
}
// row-major [row][64 bf16] tile, bank swizzle; same map on write and read
__device__ __forceinline__ int swz(int row, int byteoff) {
    return (row << 7) + (byteoff ^ ((row & 7) << 4));
}

// ---- pre-pass v2: fp32 {0,1} mask -> bitmask, coalesced byte writes ----
// Output layout (bytes): [b][col64][row][bytecol]; u64 at [b][col64][row]
// has bit k = mask[b][row][col64*64 + k].
__global__ __launch_bounds__(256)
void pack_mask(const float* __restrict__ M, unsigned char* __restrict__ BM)
{
    const int t = blockIdx.x * 256 + threadIdx.x;   // 0 .. 1048575
    const int bytecol = t & 7;
    const int row     = (t >> 3) & 2047;
    const int col64   = (t >> 14) & 31;
    const int b       = t >> 19;
    const float* src = M + ((size_t)b * 2048 + row) * 2048 + col64 * 64 + bytecol * 8;
    fx4 a = *(const fx4*)src;
    fx4 c = *(const fx4*)(src + 4);
    unsigned bits = (a[0] > 0.5f)
                  | ((unsigned)(a[1] > 0.5f) << 1)
                  | ((unsigned)(a[2] > 0.5f) << 2)
                  | ((unsigned)(a[3] > 0.5f) << 3)
                  | ((unsigned)(c[0] > 0.5f) << 4)
                  | ((unsigned)(c[1] > 0.5f) << 5)
                  | ((unsigned)(c[2] > 0.5f) << 6)
                  | ((unsigned)(c[3] > 0.5f) << 7);
    BM[t] = (unsigned char)bits;
}

__global__ __launch_bounds__(512, 4)
void attn_fwd(const float* __restrict__ Qg, const float* __restrict__ Kg,
              const float* __restrict__ Vg,
              const unsigned long long* __restrict__ BMg,
              float* __restrict__ Og)
{
    // per kg: K 8KB + V^T 8KB at smem + kg*16384; epilogue reuses [0,36864)
    __shared__ __align__(16) char smem[36864];

    const int tid  = threadIdx.x;
    const int lane = tid & 63;
    const int wave = tid >> 6;   // 0..7
    const int qw   = wave & 3;   // q-strip within block
    const int kg   = wave >> 2;  // split-K group: keys [kg*1024, kg*1024+1024)
    const int lq   = lane & 31;  // q row (MFMA col)
    const int hf   = lane >> 5;  // half-wave (k-slice selector)

    short* kb = (short*)(smem + kg * 16384);
    short* vb = (short*)(smem + kg * 16384 + 8192);

    // XCD-aware bijective swizzle: 512 blocks, 64 contiguous per XCD
    const int flat = blockIdx.x + (int)gridDim.x * blockIdx.y;   // 0..511
    const int nsw  = (flat & 7) * 64 + (flat >> 3);
    const int qt = nsw & 15;
    const int bh = nsw >> 4;
    const int b  = bh >> 4;

    const int qbase = qt * BQ + qw * 32;

    const float* Kp = Kg + ((size_t)bh * S_LEN + kg * KHALF) * D_KV;
    const float* Vp = Vg + ((size_t)bh * S_LEN + kg * KHALF) * D_KV;
    const float* Qp = Qg + ((size_t)bh * S_LEN + qbase) * D_KV;
    // bitmask: [b][col64][qrow]; this wave starts at col64 = kg*NT
    const unsigned long long* BMp =
        BMg + (size_t)b * 32 * 2048 + (size_t)(kg * NT) * 2048 + qbase + lq;

    // ---- Q as 32x32x16 B-frags; scale (1/8)*log2(e): exp() -> native exp2 ----
    const float QS = 0.125f * 1.44269504f;
    bh8 qf[4];
#pragma unroll
    for (int ks = 0; ks < 4; ++ks) {
        const float* src = Qp + lq * D_KV + ks * 16 + hf * 8;
        fx4 a0 = *(const fx4*)src;
        fx4 a1 = *(const fx4*)(src + 4);
        u32x4 q4 = { cvt2(a0[0] * QS, a0[1] * QS),
                     cvt2(a0[2] * QS, a0[3] * QS),
                     cvt2(a1[0] * QS, a1[1] * QS),
                     cvt2(a1[2] * QS, a1[3] * QS) };
        qf[ks] = __builtin_bit_cast(bh8, q4);
    }

    // ---- staging maps: each kg's 256 threads stage its own K/V tile ----
    const int stid  = tid & 255;
    const int krow  = stid >> 2;           // K: 4 threads per row
    const int kcolf = (stid & 3) << 4;     // 16 CONTIGUOUS floats per thread
    const int vd0   = (stid >> 4) << 2;    // V: 4x4 transpose block
    const int vk0   = (stid & 15) << 2;

    fx16 o0 = {}, o1 = {};                 // O^T[d][q=lq], d-blocks 0/1
    float lsum = 0.f;
    fx4 kreg[4], vreg[4];                  // T14 prefetch registers

    auto issue = [&](int kt) {
        const float* ksrc = Kp + (size_t)(kt + krow) * D_KV + kcolf;
#pragma unroll
        for (int i = 0; i < 4; ++i)
            kreg[i] = *(const fx4*)(ksrc + 4 * i);
#pragma unroll
        for (int i = 0; i < 4; ++i)
            vreg[i] = *(const fx4*)(Vp + (size_t)(kt + vk0 + i) * D_KV + vd0);
    };

    issue(0);   // prologue prefetch

#pragma unroll 1
    for (int t = 0; t < NT; ++t) {
        // ---- bitmask for this tile: ONE 8B load per lane ----
        const unsigned long long bm = BMp[(size_t)t * 2048];

        // ---- drain prefetched K/V regs -> swizzled LDS ----
        // K: two b128 writes of 16 contiguous bf16 (conflict-free under swz)
#pragma unroll
        for (int j = 0; j < 2; ++j) {
            u32x4 w = { cvt2(kreg[2*j][0],   kreg[2*j][1]),
                        cvt2(kreg[2*j][2],   kreg[2*j][3]),
                        cvt2(kreg[2*j+1][0], kreg[2*j+1][1]),
                        cvt2(kreg[2*j+1][2], kreg[2*j+1][3]) };
            *(u32x4*)((char*)kb + swz(krow, (kcolf << 1) + 16 * j)) = w;
        }
#pragma unroll
        for (int i = 0; i < 4; ++i) {
            u32x2 w = { cvt2(vreg[0][i], vreg[1][i]),
                        cvt2(vreg[2][i], vreg[3][i]) };
            *(u32x2*)((char*)vb + swz(vd0 + i, vk0 << 1)) = w;
        }
        // publish ds writes only; global prefetch never vmcnt-drained here
        asm volatile("s_waitcnt lgkmcnt(0)" ::: "memory");
        __builtin_amdgcn_s_barrier();

        // ---- prefetch next tile; stays in flight across the whole compute ----
        if (t + 1 < NT) issue((t + 1) * BK);

        // ---- QK^T swapped: st = mfma(K, Q) = S^T[key][q=lq] ----
        // key(reg r, rb) = rb*32 + 8*(r>>2) + 4*hf + (r&3)
        fx16 st0 = {}, st1 = {};
        __builtin_amdgcn_s_setprio(1);
#pragma unroll
        for (int ks = 0; ks < 4; ++ks) {
            bh8 k0 = *(const bh8*)((char*)kb + swz(lq,      ks * 32 + hf * 16));
            bh8 k1 = *(const bh8*)((char*)kb + swz(32 + lq, ks * 32 + hf * 16));
            st0 = __builtin_amdgcn_mfma_f32_32x32x16_bf16(k0, qf[ks], st0, 0, 0, 0);
            st1 = __builtin_amdgcn_mfma_f32_32x32x16_bf16(k1, qf[ks], st1, 0, 0, 0);
        }
        __builtin_amdgcn_s_setprio(0);

        // per-half-wave aligned bit windows
        const unsigned s0 = ((unsigned)bm) >> (hf * 4);
        const unsigned s1 = ((unsigned)(bm >> 32)) >> (hf * 4);

        unsigned pkw[16];

        // ---- softmax rb=0: keep iff (bit && s>0); p = exp2(s*log2e) ----
#pragma unroll
        for (int m = 0; m < 4; ++m) {
            const unsigned bb = s0 >> (8 * m);
            float tm0 = st0[4*m+0], tm1 = st0[4*m+1];
            float tm2 = st0[4*m+2], tm3 = st0[4*m+3];
            float p0 = ((bb      & 1) && tm0 > 0.f) ? exp2_fast(tm0) : 0.f;
            float p1 = ((bb >> 1 & 1) && tm1 > 0.f) ? exp2_fast(tm1) : 0.f;
            float p2 = ((bb >> 2 & 1) && tm2 > 0.f) ? exp2_fast(tm2) : 0.f;
            float p3 = ((bb >> 3 & 1) && tm3 > 0.f) ? exp2_fast(tm3) : 0.f;
            lsum += (p0 + p1) + (p2 + p3);
            pkw[m*2+0] = cvt2(p0, p1);
            pkw[m*2+1] = cvt2(p2, p3);
        }

        // ---- PV keys 0..31 (B-frag via permlane32_swap, round-4-verified) ----
        __builtin_amdgcn_s_setprio(1);
#pragma unroll
        for (int vp = 0; vp < 2; ++vp) {
            unsigned w0 = pkw[vp*4+0], w1 = pkw[vp*4+1];
            unsigned w2 = pkw[vp*4+2], w3 = pkw[vp*4+3];
            swap32(w0, w2); swap32(w1, w3);
            u32x4 pq = { w0, w1, w2, w3 };
            bh8 pb = __builtin_bit_cast(bh8, pq);
            bh8 v0 = *(const bh8*)((char*)vb + swz(lq,      vp * 32 + hf * 16));
            bh8 v1 = *(const bh8*)((char*)vb + swz(32 + lq, vp * 32 + hf * 16));
            o0 = __builtin_amdgcn_mfma_f32_32x32x16_bf16(v0, pb, o0, 0, 0, 0);
            o1 = __builtin_amdgcn_mfma_f32_32x32x16_bf16(v1, pb, o1, 0, 0, 0);
        }
        __builtin_amdgcn_s_setprio(0);

        // ---- softmax rb=1 ----
#pragma unroll
        for (int m = 0; m < 4; ++m) {
            const unsigned bb = s1 >> (8 * m);
            float tm0 = st1[4*m+0], tm1 = st1[4*m+1];
            float tm2 = st1[4*m+2], tm3 = st1[4*m+3];
            float p0 = ((bb      & 1) && tm0 > 0.f) ? exp2_fast(tm0) : 0.f;
            float p1 = ((bb >> 1 & 1) && tm1 > 0.f) ? exp2_fast(tm1) : 0.f;
            float p2 = ((bb >> 2 & 1) && tm2 > 0.f) ? exp2_fast(tm2) : 0.f;
            float p3 = ((bb >> 3 & 1) && tm3 > 0.f) ? exp2_fast(tm3) : 0.f;
            lsum += (p0 + p1) + (p2 + p3);
            pkw[8 + m*2+0] = cvt2(p0, p1);
            pkw[8 + m*2+1] = cvt2(p2, p3);
        }

        // ---- PV keys 32..63 ----
        __builtin_amdgcn_s_setprio(1);
#pragma unroll
        for (int vp = 2; vp < 4; ++vp) {
            unsigned w0 = pkw[vp*4+0], w1 = pkw[vp*4+1];
            unsigned w2 = pkw[vp*4+2], w3 = pkw[vp*4+3];
            swap32(w0, w2); swap32(w1, w3);
            u32x4 pq = { w0, w1, w2, w3 };
            bh8 pb = __builtin_bit_cast(bh8, pq);
            bh8 v0 = *(const bh8*)((char*)vb + swz(lq,      vp * 32 + hf * 16));
            bh8 v1 = *(const bh8*)((char*)vb + swz(32 + lq, vp * 32 + hf * 16));
            o0 = __builtin_amdgcn_mfma_f32_32x32x16_bf16(v0, pb, o0, 0, 0, 0);
            o1 = __builtin_amdgcn_mfma_f32_32x32x16_bf16(v1, pb, o1, 0, 0, 0);
        }
        __builtin_amdgcn_s_setprio(0);

        // all LDS reads retired (consumed by MFMA); barrier alone orders waves
        __builtin_amdgcn_s_barrier();
    }

    // ---- per-group row sum across half-waves (same q, complementary keys) ----
    lsum += __shfl_xor(lsum, 32);

    // ---- split-K combine: fixed-max softmax => partials add linearly ----
    float* scr = (float*)smem;             // 256 slots x 36 floats = 36864 B
    const int slot = qw * 64 + lane;
    if (kg) {
        float* d = scr + slot * 36;
#pragma unroll
        for (int i = 0; i < 4; ++i) {
            fx4 c0 = { o0[4*i+0], o0[4*i+1], o0[4*i+2], o0[4*i+3] };
            *(fx4*)(d + 4 * i) = c0;
            fx4 c1 = { o1[4*i+0], o1[4*i+1], o1[4*i+2], o1[4*i+3] };
            *(fx4*)(d + 16 + 4 * i) = c1;
        }
        d[32] = lsum;
    }
    __syncthreads();
    if (!kg) {
        const float* s = scr + slot * 36;
#pragma unroll
        for (int i = 0; i < 4; ++i) {
            fx4 c0 = *(const fx4*)(s + 4 * i);
            o0[4*i+0] += c0[0]; o0[4*i+1] += c0[1];
            o0[4*i+2] += c0[2]; o0[4*i+3] += c0[3];
            fx4 c1 = *(const fx4*)(s + 16 + 4 * i);
            o1[4*i+0] += c1[0]; o1[4*i+1] += c1[1];
            o1[4*i+2] += c1[2]; o1[4*i+3] += c1[3];
        }
        lsum += s[32];
        const float inv = 1.0f / lsum;

        // epilogue: O[q][d], d = db*32 + 8m + 4*hf + j
        float* orow = Og + ((size_t)bh * S_LEN + qbase + lq) * D_KV;
#pragma unroll
        for (int m = 0; m < 4; ++m) {
            fx4 r0 = { o0[4*m+0]*inv, o0[4*m+1]*inv, o0[4*m+2]*inv, o0[4*m+3]*inv };
            *(fx4*)(orow + m * 8 + hf * 4) = r0;
            fx4 r1 = { o1[4*m+0]*inv, o1[4*m+1]*inv, o1[4*m+2]*inv, o1[4*m+3]*inv };
            *(fx4*)(orow + 32 + m * 8 + hf * 4) = r1;
        }
    }
}

extern "C" void kernel_launch(void* const* d_in, const int* in_sizes, int n_in,
                              void* d_out, int out_size, void* d_ws, size_t ws_size,
                              hipStream_t stream) {
    const float* Q = (const float*)d_in[0];
    const float* K = (const float*)d_in[1];
    const float* V = (const float*)d_in[2];
    const float* M = (const float*)d_in[3];
    float*       O = (float*)d_out;

    // pack mask: 2*2048*2048 elems / 8 per thread / 256 = 4096 blocks
    pack_mask<<<dim3(4096), 256, 0, stream>>>(M, (unsigned char*)d_ws);

    dim3 grid(S_LEN / BQ, 32);   // 16 q-tiles x (B*H)=32
    attn_fwd<<<grid, 512, 0, stream>>>(Q, K, V,
                                       (const unsigned long long*)d_ws, O);
}

// Round 8
// 217.350 us; speedup vs baseline: 1.3484x; 1.3484x over previous
//
#include <hip/hip_runtime.h>
#include <math.h>

#define S_LEN 2048
#define D_KV  64
#define BQ    128   // q rows per block: 4 q-waves x 32 (x2 split-K groups)
#define BK    64
#define KHALF 1024
#define NT    (KHALF / BK)   // 16 k-tiles per split-K group

typedef __attribute__((ext_vector_type(8)))  short bh8;   // 8 bf16 (MFMA A/B frag)
typedef __attribute__((ext_vector_type(4)))  float fx4;
typedef __attribute__((ext_vector_type(16))) float fx16;  // 32x32 MFMA C/D frag
typedef __attribute__((ext_vector_type(4)))  unsigned int u32x4;
typedef __attribute__((ext_vector_type(2)))  unsigned int u32x2;

__device__ __forceinline__ unsigned cvt2(float a, float b) {
    unsigned r;
    asm("v_cvt_pk_bf16_f32 %0, %1, %2" : "=v"(r) : "v"(a), "v"(b));
    return r;
}
// v_permlane32_swap_b32 d, s: exchanges d lanes 32-63 with s lanes 0-31.
__device__ __forceinline__ void swap32(unsigned &d, unsigned &s) {
    asm("v_permlane32_swap_b32 %0, %1" : "+v"(d), "+v"(s));
}
__device__ __forceinline__ float exp2_fast(float x) {   // native 2^x
    float r;
    asm("v_exp_f32 %0, %1" : "=v"(r) : "v"(x));
    return r;
}
// row-major [row][64 bf16] tile, bank swizzle; same map on write and read
__device__ __forceinline__ int swz(int row, int byteoff) {
    return (row << 7) + (byteoff ^ ((row & 7) << 4));
}

// ---- pre-pass: fp32 {0,1} mask -> bitmask, coalesced byte writes ----
// Output layout (bytes): [b][col64][row][bytecol]; u64 at [b][col64][row]
// has bit k = mask[b][row][col64*64 + k].
__global__ __launch_bounds__(256)
void pack_mask(const float* __restrict__ M, unsigned char* __restrict__ BM)
{
    const int t = blockIdx.x * 256 + threadIdx.x;   // 0 .. 1048575
    const int bytecol = t & 7;
    const int row     = (t >> 3) & 2047;
    const int col64   = (t >> 14) & 31;
    const int b       = t >> 19;
    const float* src = M + ((size_t)b * 2048 + row) * 2048 + col64 * 64 + bytecol * 8;
    fx4 a = *(const fx4*)src;
    fx4 c = *(const fx4*)(src + 4);
    unsigned bits = (a[0] > 0.5f)
                  | ((unsigned)(a[1] > 0.5f) << 1)
                  | ((unsigned)(a[2] > 0.5f) << 2)
                  | ((unsigned)(a[3] > 0.5f) << 3)
                  | ((unsigned)(c[0] > 0.5f) << 4)
                  | ((unsigned)(c[1] > 0.5f) << 5)
                  | ((unsigned)(c[2] > 0.5f) << 6)
                  | ((unsigned)(c[3] > 0.5f) << 7);
    BM[t] = (unsigned char)bits;
}

// NOTE: 2nd launch_bounds arg = min WAVES PER EU; compiler VGPR cap ≈ 256/arg.
// (512,4) capped at 64 VGPR -> spilled accumulators (round 7). (512,2) -> 128.
__global__ __launch_bounds__(512, 2)
void attn_fwd(const float* __restrict__ Qg, const float* __restrict__ Kg,
              const float* __restrict__ Vg,
              const unsigned long long* __restrict__ BMg,
              float* __restrict__ Og)
{
    // per kg: K 8KB + V^T 8KB at smem + kg*16384; epilogue reuses [0,36864)
    __shared__ __align__(16) char smem[36864];

    const int tid  = threadIdx.x;
    const int lane = tid & 63;
    const int wave = tid >> 6;   // 0..7
    const int qw   = wave & 3;   // q-strip within block
    const int kg   = wave >> 2;  // split-K group: keys [kg*1024, kg*1024+1024)
    const int lq   = lane & 31;  // q row (MFMA col)
    const int hf   = lane >> 5;  // half-wave (k-slice selector)

    short* kb = (short*)(smem + kg * 16384);
    short* vb = (short*)(smem + kg * 16384 + 8192);

    // XCD-aware bijective swizzle: 512 blocks, 64 contiguous per XCD
    const int flat = blockIdx.x + (int)gridDim.x * blockIdx.y;   // 0..511
    const int nsw  = (flat & 7) * 64 + (flat >> 3);
    const int qt = nsw & 15;
    const int bh = nsw >> 4;
    const int b  = bh >> 4;

    const int qbase = qt * BQ + qw * 32;

    const float* Kp = Kg + ((size_t)bh * S_LEN + kg * KHALF) * D_KV;
    const float* Vp = Vg + ((size_t)bh * S_LEN + kg * KHALF) * D_KV;
    const float* Qp = Qg + ((size_t)bh * S_LEN + qbase) * D_KV;
    // bitmask: [b][col64][qrow]; this wave starts at col64 = kg*NT
    const unsigned long long* BMp =
        BMg + (size_t)b * 32 * 2048 + (size_t)(kg * NT) * 2048 + qbase + lq;

    // ---- Q as 32x32x16 B-frags; scale (1/8)*log2(e): exp() -> native exp2 ----
    const float QS = 0.125f * 1.44269504f;
    bh8 qf[4];
#pragma unroll
    for (int ks = 0; ks < 4; ++ks) {
        const float* src = Qp + lq * D_KV + ks * 16 + hf * 8;
        fx4 a0 = *(const fx4*)src;
        fx4 a1 = *(const fx4*)(src + 4);
        u32x4 q4 = { cvt2(a0[0] * QS, a0[1] * QS),
                     cvt2(a0[2] * QS, a0[3] * QS),
                     cvt2(a1[0] * QS, a1[1] * QS),
                     cvt2(a1[2] * QS, a1[3] * QS) };
        qf[ks] = __builtin_bit_cast(bh8, q4);
    }

    // ---- staging maps: each kg's 256 threads stage its own K/V tile ----
    const int stid  = tid & 255;
    const int krow  = stid >> 2;           // K: 4 threads per row
    const int kcolf = (stid & 3) << 4;     // 16 CONTIGUOUS floats per thread
    const int vd0   = (stid >> 4) << 2;    // V: 4x4 transpose block
    const int vk0   = (stid & 15) << 2;

    fx16 o0 = {}, o1 = {};                 // O^T[d][q=lq], d-blocks 0/1
    float lsum = 0.f;
    fx4 kreg[4], vreg[4];                  // T14 prefetch registers

    auto issue = [&](int kt) {
        const float* ksrc = Kp + (size_t)(kt + krow) * D_KV + kcolf;
#pragma unroll
        for (int i = 0; i < 4; ++i)
            kreg[i] = *(const fx4*)(ksrc + 4 * i);
#pragma unroll
        for (int i = 0; i < 4; ++i)
            vreg[i] = *(const fx4*)(Vp + (size_t)(kt + vk0 + i) * D_KV + vd0);
    };

    issue(0);   // prologue prefetch

#pragma unroll 1
    for (int t = 0; t < NT; ++t) {
        // ---- bitmask for this tile: ONE 8B load per lane ----
        const unsigned long long bm = BMp[(size_t)t * 2048];

        // ---- drain prefetched K/V regs -> swizzled LDS ----
        // K: two b128 writes of 16 contiguous bf16 (conflict-free under swz)
#pragma unroll
        for (int j = 0; j < 2; ++j) {
            u32x4 w = { cvt2(kreg[2*j][0],   kreg[2*j][1]),
                        cvt2(kreg[2*j][2],   kreg[2*j][3]),
                        cvt2(kreg[2*j+1][0], kreg[2*j+1][1]),
                        cvt2(kreg[2*j+1][2], kreg[2*j+1][3]) };
            *(u32x4*)((char*)kb + swz(krow, (kcolf << 1) + 16 * j)) = w;
        }
#pragma unroll
        for (int i = 0; i < 4; ++i) {
            u32x2 w = { cvt2(vreg[0][i], vreg[1][i]),
                        cvt2(vreg[2][i], vreg[3][i]) };
            *(u32x2*)((char*)vb + swz(vd0 + i, vk0 << 1)) = w;
        }
        // publish ds writes only; global prefetch never vmcnt-drained here
        asm volatile("s_waitcnt lgkmcnt(0)" ::: "memory");
        __builtin_amdgcn_s_barrier();

        // ---- prefetch next tile; stays in flight across the whole compute ----
        if (t + 1 < NT) issue((t + 1) * BK);

        // ---- QK^T swapped: st = mfma(K, Q) = S^T[key][q=lq] ----
        // key(reg r, rb) = rb*32 + 8*(r>>2) + 4*hf + (r&3)
        fx16 st0 = {}, st1 = {};
        __builtin_amdgcn_s_setprio(1);
#pragma unroll
        for (int ks = 0; ks < 4; ++ks) {
            bh8 k0 = *(const bh8*)((char*)kb + swz(lq,      ks * 32 + hf * 16));
            bh8 k1 = *(const bh8*)((char*)kb + swz(32 + lq, ks * 32 + hf * 16));
            st0 = __builtin_amdgcn_mfma_f32_32x32x16_bf16(k0, qf[ks], st0, 0, 0, 0);
            st1 = __builtin_amdgcn_mfma_f32_32x32x16_bf16(k1, qf[ks], st1, 0, 0, 0);
        }
        __builtin_amdgcn_s_setprio(0);

        // per-half-wave aligned bit windows
        const unsigned s0 = ((unsigned)bm) >> (hf * 4);
        const unsigned s1 = ((unsigned)(bm >> 32)) >> (hf * 4);

        unsigned pkw[16];

        // ---- softmax rb=0: keep iff (bit && s>0); p = exp2(s*log2e) ----
#pragma unroll
        for (int m = 0; m < 4; ++m) {
            const unsigned bb = s0 >> (8 * m);
            float tm0 = st0[4*m+0], tm1 = st0[4*m+1];
            float tm2 = st0[4*m+2], tm3 = st0[4*m+3];
            float p0 = ((bb      & 1) && tm0 > 0.f) ? exp2_fast(tm0) : 0.f;
            float p1 = ((bb >> 1 & 1) && tm1 > 0.f) ? exp2_fast(tm1) : 0.f;
            float p2 = ((bb >> 2 & 1) && tm2 > 0.f) ? exp2_fast(tm2) : 0.f;
            float p3 = ((bb >> 3 & 1) && tm3 > 0.f) ? exp2_fast(tm3) : 0.f;
            lsum += (p0 + p1) + (p2 + p3);
            pkw[m*2+0] = cvt2(p0, p1);
            pkw[m*2+1] = cvt2(p2, p3);
        }

        // ---- PV keys 0..31 (B-frag via permlane32_swap, round-4-verified) ----
        __builtin_amdgcn_s_setprio(1);
#pragma unroll
        for (int vp = 0; vp < 2; ++vp) {
            unsigned w0 = pkw[vp*4+0], w1 = pkw[vp*4+1];
            unsigned w2 = pkw[vp*4+2], w3 = pkw[vp*4+3];
            swap32(w0, w2); swap32(w1, w3);
            u32x4 pq = { w0, w1, w2, w3 };
            bh8 pb = __builtin_bit_cast(bh8, pq);
            bh8 v0 = *(const bh8*)((char*)vb + swz(lq,      vp * 32 + hf * 16));
            bh8 v1 = *(const bh8*)((char*)vb + swz(32 + lq, vp * 32 + hf * 16));
            o0 = __builtin_amdgcn_mfma_f32_32x32x16_bf16(v0, pb, o0, 0, 0, 0);
            o1 = __builtin_amdgcn_mfma_f32_32x32x16_bf16(v1, pb, o1, 0, 0, 0);
        }
        __builtin_amdgcn_s_setprio(0);

        // ---- softmax rb=1 ----
#pragma unroll
        for (int m = 0; m < 4; ++m) {
            const unsigned bb = s1 >> (8 * m);
            float tm0 = st1[4*m+0], tm1 = st1[4*m+1];
            float tm2 = st1[4*m+2], tm3 = st1[4*m+3];
            float p0 = ((bb      & 1) && tm0 > 0.f) ? exp2_fast(tm0) : 0.f;
            float p1 = ((bb >> 1 & 1) && tm1 > 0.f) ? exp2_fast(tm1) : 0.f;
            float p2 = ((bb >> 2 & 1) && tm2 > 0.f) ? exp2_fast(tm2) : 0.f;
            float p3 = ((bb >> 3 & 1) && tm3 > 0.f) ? exp2_fast(tm3) : 0.f;
            lsum += (p0 + p1) + (p2 + p3);
            pkw[8 + m*2+0] = cvt2(p0, p1);
            pkw[8 + m*2+1] = cvt2(p2, p3);
        }

        // ---- PV keys 32..63 ----
        __builtin_amdgcn_s_setprio(1);
#pragma unroll
        for (int vp = 2; vp < 4; ++vp) {
            unsigned w0 = pkw[vp*4+0], w1 = pkw[vp*4+1];
            unsigned w2 = pkw[vp*4+2], w3 = pkw[vp*4+3];
            swap32(w0, w2); swap32(w1, w3);
            u32x4 pq = { w0, w1, w2, w3 };
            bh8 pb = __builtin_bit_cast(bh8, pq);
            bh8 v0 = *(const bh8*)((char*)vb + swz(lq,      vp * 32 + hf * 16));
            bh8 v1 = *(const bh8*)((char*)vb + swz(32 + lq, vp * 32 + hf * 16));
            o0 = __builtin_amdgcn_mfma_f32_32x32x16_bf16(v0, pb, o0, 0, 0, 0);
            o1 = __builtin_amdgcn_mfma_f32_32x32x16_bf16(v1, pb, o1, 0, 0, 0);
        }
        __builtin_amdgcn_s_setprio(0);

        // all LDS reads retired (consumed by MFMA); barrier alone orders waves
        __builtin_amdgcn_s_barrier();
    }

    // ---- per-group row sum across half-waves (same q, complementary keys) ----
    lsum += __shfl_xor(lsum, 32);

    // ---- split-K combine: fixed-max softmax => partials add linearly ----
    float* scr = (float*)smem;             // 256 slots x 36 floats = 36864 B
    const int slot = qw * 64 + lane;
    if (kg) {
        float* d = scr + slot * 36;
#pragma unroll
        for (int i = 0; i < 4; ++i) {
            fx4 c0 = { o0[4*i+0], o0[4*i+1], o0[4*i+2], o0[4*i+3] };
            *(fx4*)(d + 4 * i) = c0;
            fx4 c1 = { o1[4*i+0], o1[4*i+1], o1[4*i+2], o1[4*i+3] };
            *(fx4*)(d + 16 + 4 * i) = c1;
        }
        d[32] = lsum;
    }
    __syncthreads();
    if (!kg) {
        const float* s = scr + slot * 36;
#pragma unroll
        for (int i = 0; i < 4; ++i) {
            fx4 c0 = *(const fx4*)(s + 4 * i);
            o0[4*i+0] += c0[0]; o0[4*i+1] += c0[1];
            o0[4*i+2] += c0[2]; o0[4*i+3] += c0[3];
            fx4 c1 = *(const fx4*)(s + 16 + 4 * i);
            o1[4*i+0] += c1[0]; o1[4*i+1] += c1[1];
            o1[4*i+2] += c1[2]; o1[4*i+3] += c1[3];
        }
        lsum += s[32];
        const float inv = 1.0f / lsum;

        // epilogue: O[q][d], d = db*32 + 8m + 4*hf + j
        float* orow = Og + ((size_t)bh * S_LEN + qbase + lq) * D_KV;
#pragma unroll
        for (int m = 0; m < 4; ++m) {
            fx4 r0 = { o0[4*m+0]*inv, o0[4*m+1]*inv, o0[4*m+2]*inv, o0[4*m+3]*inv };
            *(fx4*)(orow + m * 8 + hf * 4) = r0;
            fx4 r1 = { o1[4*m+0]*inv, o1[4*m+1]*inv, o1[4*m+2]*inv, o1[4*m+3]*inv };
            *(fx4*)(orow + 32 + m * 8 + hf * 4) = r1;
        }
    }
}

extern "C" void kernel_launch(void* const* d_in, const int* in_sizes, int n_in,
                              void* d_out, int out_size, void* d_ws, size_t ws_size,
                              hipStream_t stream) {
    const float* Q = (const float*)d_in[0];
    const float* K = (const float*)d_in[1];
    const float* V = (const float*)d_in[2];
    const float* M = (const float*)d_in[3];
    float*       O = (float*)d_out;

    // pack mask: 2*2048*2048 elems / 8 per thread / 256 = 4096 blocks
    pack_mask<<<dim3(4096), 256, 0, stream>>>(M, (unsigned char*)d_ws);

    dim3 grid(S_LEN / BQ, 32);   // 16 q-tiles x (B*H)=32
    attn_fwd<<<grid, 512, 0, stream>>>(Q, K, V,
                                       (const unsigned long long*)d_ws, O);
}